// Round 2
// baseline (12401.189 us; speedup 1.0000x reference)
//
#include <hip/hip_runtime.h>
#include <hip/hip_bf16.h>

#define TT 2048
#define EE 256
#define HH 512
#define KK 48
#define START_TAG 45
#define END_TAG 46
#define NEGV -100000.0f

// ---------------------------------------------------------------- embedding
__global__ void gather_kernel(const int* __restrict__ tokens,
                              const float* __restrict__ embed,
                              float* __restrict__ x) {
    int t = blockIdx.x;
    int e = threadIdx.x;                       // 256 threads = E
    x[(size_t)t * EE + e] = embed[(size_t)tokens[t] * EE + e];
}

// ---------------------------------------------------------------- fp32 GEMM
// C[M,N] = A[M,Kd] @ B[N,Kd]^T + bias1[n] + bias2[n]
// M,N multiples of 128, Kd multiple of 16. 256 threads, 128x128 tile, 8x8/thread.
__global__ __launch_bounds__(256) void gemm_bt128(
    const float* __restrict__ A, const float* __restrict__ B,
    float* __restrict__ C, int M, int N, int Kd,
    const float* __restrict__ bias1, const float* __restrict__ bias2) {
    __shared__ float As[16][132];
    __shared__ float Bs[16][132];
    const int bm = blockIdx.y * 128, bn = blockIdx.x * 128;
    const int tid = threadIdx.x;
    const int tx = tid & 15, ty = tid >> 4;

    float acc[8][8];
#pragma unroll
    for (int i = 0; i < 8; ++i)
#pragma unroll
        for (int j = 0; j < 8; ++j) acc[i][j] = 0.f;

    const int ar = tid >> 1, kc = (tid & 1) * 8;

    for (int k0 = 0; k0 < Kd; k0 += 16) {
        const float* pa = A + (size_t)(bm + ar) * Kd + k0 + kc;
        float4 a0 = *(const float4*)pa;
        float4 a1 = *(const float4*)(pa + 4);
        As[kc + 0][ar] = a0.x; As[kc + 1][ar] = a0.y;
        As[kc + 2][ar] = a0.z; As[kc + 3][ar] = a0.w;
        As[kc + 4][ar] = a1.x; As[kc + 5][ar] = a1.y;
        As[kc + 6][ar] = a1.z; As[kc + 7][ar] = a1.w;
        const float* pb = B + (size_t)(bn + ar) * Kd + k0 + kc;
        float4 b0 = *(const float4*)pb;
        float4 b1 = *(const float4*)(pb + 4);
        Bs[kc + 0][ar] = b0.x; Bs[kc + 1][ar] = b0.y;
        Bs[kc + 2][ar] = b0.z; Bs[kc + 3][ar] = b0.w;
        Bs[kc + 4][ar] = b1.x; Bs[kc + 5][ar] = b1.y;
        Bs[kc + 6][ar] = b1.z; Bs[kc + 7][ar] = b1.w;
        __syncthreads();
#pragma unroll
        for (int kk = 0; kk < 16; ++kk) {
            const float4* ap = (const float4*)&As[kk][ty * 8];
            const float4* bp = (const float4*)&Bs[kk][tx * 8];
            float4 av0 = ap[0], av1 = ap[1];
            float4 bv0 = bp[0], bv1 = bp[1];
            float a[8] = {av0.x, av0.y, av0.z, av0.w, av1.x, av1.y, av1.z, av1.w};
            float b[8] = {bv0.x, bv0.y, bv0.z, bv0.w, bv1.x, bv1.y, bv1.z, bv1.w};
#pragma unroll
            for (int i = 0; i < 8; ++i)
#pragma unroll
                for (int j = 0; j < 8; ++j) acc[i][j] += a[i] * b[j];
        }
        __syncthreads();
    }
#pragma unroll
    for (int i = 0; i < 8; ++i) {
        size_t row = (size_t)(bm + ty * 8 + i) * N + bn;
#pragma unroll
        for (int j = 0; j < 8; ++j) {
            int n = tx * 8 + j;
            C[row + n] = acc[i][j] + bias1[bn + n] + bias2[bn + n];
        }
    }
}

// ---------------------------------------------------------------- LSTM recurrence
// One layer, both directions. 64 WGs x 256 threads.
//   wg 0..31 -> forward (units g*16..g*16+15), wg 32..63 -> backward.
// Row mapping is UNIT-MAJOR: r = 4*u + gate so a unit's 4 gates live in one
// wave and combine via shfl_down — no second barrier, no gate-LDS phase.
// h exchanged via tagged 8B slots (value|step-tag), relaxed agent atomics.
__global__ __launch_bounds__(256) void lstm_recur(
    const float* __restrict__ Zf, const float* __restrict__ Zb,
    const float* __restrict__ Whf, const float* __restrict__ Whb,
    unsigned long long* commF, unsigned long long* commB,
    float* __restrict__ hseq, unsigned tagbase) {
    const int wg = blockIdx.x;
    const int dir = wg >> 5;
    const int g = wg & 31;
    const float* Z = dir ? Zb : Zf;
    const float* Wh = dir ? Whb : Whf;
    unsigned long long* comm = dir ? commB : commF;

    const int tid = threadIdx.x;
    const int q = tid & 3;             // quarter of the 512-wide row
    const int r = tid >> 2;            // local row 0..63, r = 4*u + gate
    const int gate = r & 3;            // 0..3 = (i,f,g,o)
    const int u = r >> 2;              // unit within this WG, 0..15
    const int R = gate * HH + g * 16 + u;   // global gate-row in [0,2048)

    float w[128];
    {
        const float* wp = Wh + (size_t)R * HH + q * 128;
#pragma unroll
        for (int k = 0; k < 128; k += 4) {
            float4 v = *(const float4*)(wp + k);
            w[k] = v.x; w[k + 1] = v.y; w[k + 2] = v.z; w[k + 3] = v.w;
        }
    }

    // padded: 4 sections of 132 floats -> q-sections start on distinct bank quads
    __shared__ float h_sh[2][536];

    const int s0 = 2 * tid;                       // first slot this thread polls
    const int sidx = s0 + (s0 >> 7) * 4;          // padded LDS index
    const bool own = (s0 >= g * 16) && (s0 < g * 16 + 16);  // own-WG slots: skip poll
    const bool act = ((tid & 15) == 0);           // activation thread (one per unit)
    const int unit = g * 16 + (tid >> 4);         // global unit for activation thread
    const int upad = unit + (unit >> 7) * 4;      // its padded LDS index

    float c = 0.f;                                // persistent cell state (act threads)

    for (int s = 0; s < TT; ++s) {
        const int t = dir ? (TT - 1 - s) : s;
        const int buf = s & 1;
        float zv = Z[(size_t)t * 2048 + R];       // independent of h: overlaps poll

        if (s == 0) {
            h_sh[0][sidx] = 0.f;
            h_sh[0][sidx + 1] = 0.f;
        } else if (!own) {
            const unsigned exptag = tagbase + (unsigned)(s - 1);
            const unsigned long long* p = comm + (size_t)(s - 1) * HH + s0;
            unsigned long long v0 = 0, v1 = 0;
            bool r0 = false, r1 = false;
            int spins = 0;
            do {
                if (!r0) v0 = __hip_atomic_load(p, __ATOMIC_RELAXED, __HIP_MEMORY_SCOPE_AGENT);
                if (!r1) v1 = __hip_atomic_load(p + 1, __ATOMIC_RELAXED, __HIP_MEMORY_SCOPE_AGENT);
                r0 = r0 | ((unsigned)(v0 >> 32) == exptag);
                r1 = r1 | ((unsigned)(v1 >> 32) == exptag);
                if (++spins > 6) __builtin_amdgcn_s_sleep(1);
            } while (!(r0 & r1));
            h_sh[buf][sidx] = __uint_as_float((unsigned)v0);
            h_sh[buf][sidx + 1] = __uint_as_float((unsigned)v1);
        }
        __syncthreads();

        float acc = 0.f;
        const float* hp = &h_sh[buf][q * 132];
#pragma unroll
        for (int k = 0; k < 128; k += 4) {
            float4 hv = *(const float4*)(hp + k);
            acc += w[k] * hv.x + w[k + 1] * hv.y + w[k + 2] * hv.z + w[k + 3] * hv.w;
        }
        acc += __shfl_xor(acc, 1);
        acc += __shfl_xor(acc, 2);
        float v = acc + zv;                        // full gate value on all 4 q-lanes
        float gf_ = __shfl_down(v, 4);             // gate f of same unit
        float gg_ = __shfl_down(v, 8);             // gate g
        float go_ = __shfl_down(v, 12);            // gate o

        if (act) {
            float si = 1.f / (1.f + __expf(-v));
            float sf = 1.f / (1.f + __expf(-gf_));
            float so = 1.f / (1.f + __expf(-go_));
            c = sf * c + si * tanhf(gg_);
            float h = so * tanhf(c);
            unsigned long long pk =
                ((unsigned long long)(tagbase + (unsigned)s) << 32) |
                (unsigned long long)__float_as_uint(h);
            __hip_atomic_store(comm + (size_t)s * HH + unit, pk,
                               __ATOMIC_RELAXED, __HIP_MEMORY_SCOPE_AGENT);
            hseq[(size_t)t * 1024 + dir * HH + unit] = h;
            h_sh[buf ^ 1][upad] = h;               // own unit, next step's buffer
        }
    }
}

// ---------------------------------------------------------------- final linear
__global__ void feats_kernel(const float* __restrict__ h1,
                             const float* __restrict__ lw,
                             const float* __restrict__ lb,
                             float* __restrict__ feats) {
    int t = blockIdx.x;
    int j = threadIdx.x;               // 64 threads, 48 active
    if (j < KK) {
        const float* a = h1 + (size_t)t * 1024;
        const float* b = lw + (size_t)j * 1024;
        float acc = 0.f;
        for (int k = 0; k < 1024; k += 4) {
            float4 av = *(const float4*)(a + k);
            float4 bv = *(const float4*)(b + k);
            acc += av.x * bv.x + av.y * bv.y + av.z * bv.z + av.w * bv.w;
        }
        feats[(size_t)t * KK + j] = acc + lb[j];
    }
}

// ---------------------------------------------------------------- CRF
__global__ __launch_bounds__(64) void crf_kernel(
    const float* __restrict__ feats, const float* __restrict__ trans,
    const int* __restrict__ tags, const int* __restrict__ seq_len,
    float* __restrict__ out) {
    __shared__ float alpha[KK];
    __shared__ float red[64];
    __shared__ float logz_sh;
    const int j = threadIdx.x;

    float Trow[KK];
    if (j < KK) {
#pragma unroll
        for (int i = 0; i < KK; ++i) Trow[i] = trans[(size_t)j * KK + i];
        alpha[j] = (j == START_TAG) ? 0.f : NEGV;
    }
    __syncthreads();

    for (int t = 0; t < TT; ++t) {
        float na = 0.f;
        if (j < KK) {
            float fj = feats[(size_t)t * KK + j];
            float m = -3.0e38f;
#pragma unroll
            for (int i = 0; i < KK; ++i) m = fmaxf(m, alpha[i] + Trow[i]);
            float ssum = 0.f;
#pragma unroll
            for (int i = 0; i < KK; ++i) ssum += __expf(alpha[i] + Trow[i] - m);
            na = fj + m + __logf(ssum);
        }
        __syncthreads();
        if (j < KK) alpha[j] = na;
        __syncthreads();
    }

    if (j == 0) {
        float m = -3.0e38f;
        for (int i = 0; i < KK; ++i) m = fmaxf(m, alpha[i] + trans[END_TAG * KK + i]);
        float ssum = 0.f;
        for (int i = 0; i < KK; ++i) ssum += __expf(alpha[i] + trans[END_TAG * KK + i] - m);
        logz_sh = m + __logf(ssum);
    }

    float sc = 0.f;
    for (int t = j; t < TT; t += 64) {
        int cur = tags[t];
        int prev = (t == 0) ? START_TAG : tags[t - 1];
        sc += trans[(size_t)cur * KK + prev] + feats[(size_t)t * KK + cur];
    }
    red[j] = sc;
    __syncthreads();
    if (j == 0) {
        float score = 0.f;
        for (int i = 0; i < 64; ++i) score += red[i];
        score += trans[END_TAG * KK + tags[TT - 1]];
        out[0] = (logz_sh - score) / (float)seq_len[0];
    }
}

// ---------------------------------------------------------------- launch
extern "C" void kernel_launch(void* const* d_in, const int* in_sizes, int n_in,
                              void* d_out, int out_size, void* d_ws, size_t ws_size,
                              hipStream_t stream) {
    const int* tokens = (const int*)d_in[0];
    const int* tags = (const int*)d_in[1];
    const int* seq_len = (const int*)d_in[2];
    const float* embed = (const float*)d_in[3];
    const float* w_ih_l0_f = (const float*)d_in[4];
    const float* w_hh_l0_f = (const float*)d_in[5];
    const float* b_ih_l0_f = (const float*)d_in[6];
    const float* b_hh_l0_f = (const float*)d_in[7];
    const float* w_ih_l0_b = (const float*)d_in[8];
    const float* w_hh_l0_b = (const float*)d_in[9];
    const float* b_ih_l0_b = (const float*)d_in[10];
    const float* b_hh_l0_b = (const float*)d_in[11];
    const float* w_ih_l1_f = (const float*)d_in[12];
    const float* w_hh_l1_f = (const float*)d_in[13];
    const float* b_ih_l1_f = (const float*)d_in[14];
    const float* b_hh_l1_f = (const float*)d_in[15];
    const float* w_ih_l1_b = (const float*)d_in[16];
    const float* w_hh_l1_b = (const float*)d_in[17];
    const float* b_ih_l1_b = (const float*)d_in[18];
    const float* b_hh_l1_b = (const float*)d_in[19];
    const float* lin_w = (const float*)d_in[20];
    const float* lin_b = (const float*)d_in[21];
    const float* transition = (const float*)d_in[22];
    float* out = (float*)d_out;

    char* ws = (char*)d_ws;
    float* x = (float*)ws;                                        //  2 MB
    float* Zf = (float*)(ws + (size_t)(2) * (1 << 20));           // 16 MB
    float* Zb = (float*)(ws + (size_t)(18) * (1 << 20));          // 16 MB
    float* h0 = (float*)(ws + (size_t)(34) * (1 << 20));          //  8 MB
    float* h1 = (float*)(ws + (size_t)(42) * (1 << 20));          //  8 MB
    float* feats = (float*)(ws + (size_t)(50) * (1 << 20));       // .4 MB
    unsigned long long* commF = (unsigned long long*)(ws + (size_t)(51) * (1 << 20)); // 8 MB
    unsigned long long* commB = (unsigned long long*)(ws + (size_t)(59) * (1 << 20)); // 8 MB

    gather_kernel<<<TT, EE, 0, stream>>>(tokens, embed, x);

    dim3 g16(16, 16);
    gemm_bt128<<<g16, 256, 0, stream>>>(x, w_ih_l0_f, Zf, TT, 2048, EE, b_ih_l0_f, b_hh_l0_f);
    gemm_bt128<<<g16, 256, 0, stream>>>(x, w_ih_l0_b, Zb, TT, 2048, EE, b_ih_l0_b, b_hh_l0_b);

    lstm_recur<<<64, 256, 0, stream>>>(Zf, Zb, w_hh_l0_f, w_hh_l0_b, commF, commB, h0, 1u);

    gemm_bt128<<<g16, 256, 0, stream>>>(h0, w_ih_l1_f, Zf, TT, 2048, 1024, b_ih_l1_f, b_hh_l1_f);
    gemm_bt128<<<g16, 256, 0, stream>>>(h0, w_ih_l1_b, Zb, TT, 2048, 1024, b_ih_l1_b, b_hh_l1_b);

    lstm_recur<<<64, 256, 0, stream>>>(Zf, Zb, w_hh_l1_f, w_hh_l1_b, commF, commB, h1, 100000u);

    feats_kernel<<<TT, 64, 0, stream>>>(h1, lin_w, lin_b, feats);
    crf_kernel<<<1, 64, 0, stream>>>(feats, transition, tags, seq_len, out);
}

// Round 4
// 11843.935 us; speedup vs baseline: 1.0470x; 1.0470x over previous
//
#include <hip/hip_runtime.h>
#include <hip/hip_bf16.h>

#define TT 2048
#define EE 256
#define HH 512
#define KK 48
#define START_TAG 45
#define END_TAG 46
#define NEGV -100000.0f

// Raw vector type: lowers to a 4-VGPR tuple in inline asm (HIP's float4 is a
// class -> "indirect register input" error; this is the fix).
typedef float v4f __attribute__((ext_vector_type(4)));

// Coherent (cache-bypassing, device-visible) 16B load/store — same sc0/sc1
// flags agent-scope atomics lower to, but 16B wide.
__device__ __forceinline__ v4f load_coherent16(const float* p) {
    v4f v;
    asm volatile("global_load_dwordx4 %0, %1, off sc0 sc1\n\t"
                 "s_waitcnt vmcnt(0)"
                 : "=v"(v) : "v"(p) : "memory");
    return v;
}
__device__ __forceinline__ void store_coherent16(float* p, v4f v) {
    asm volatile("global_store_dwordx4 %0, %1, off sc0 sc1"
                 :: "v"(p), "v"(v) : "memory");
}

// ---------------------------------------------------------------- embedding
__global__ void gather_kernel(const int* __restrict__ tokens,
                              const float* __restrict__ embed,
                              float* __restrict__ x) {
    int t = blockIdx.x;
    int e = threadIdx.x;                       // 256 threads = E
    x[(size_t)t * EE + e] = embed[(size_t)tokens[t] * EE + e];
}

// ---------------------------------------------------------------- fp32 GEMM
__global__ __launch_bounds__(256) void gemm_bt128(
    const float* __restrict__ A, const float* __restrict__ B,
    float* __restrict__ C, int M, int N, int Kd,
    const float* __restrict__ bias1, const float* __restrict__ bias2) {
    __shared__ float As[16][132];
    __shared__ float Bs[16][132];
    const int bm = blockIdx.y * 128, bn = blockIdx.x * 128;
    const int tid = threadIdx.x;
    const int tx = tid & 15, ty = tid >> 4;

    float acc[8][8];
#pragma unroll
    for (int i = 0; i < 8; ++i)
#pragma unroll
        for (int j = 0; j < 8; ++j) acc[i][j] = 0.f;

    const int ar = tid >> 1, kc = (tid & 1) * 8;

    for (int k0 = 0; k0 < Kd; k0 += 16) {
        const float* pa = A + (size_t)(bm + ar) * Kd + k0 + kc;
        float4 a0 = *(const float4*)pa;
        float4 a1 = *(const float4*)(pa + 4);
        As[kc + 0][ar] = a0.x; As[kc + 1][ar] = a0.y;
        As[kc + 2][ar] = a0.z; As[kc + 3][ar] = a0.w;
        As[kc + 4][ar] = a1.x; As[kc + 5][ar] = a1.y;
        As[kc + 6][ar] = a1.z; As[kc + 7][ar] = a1.w;
        const float* pb = B + (size_t)(bn + ar) * Kd + k0 + kc;
        float4 b0 = *(const float4*)pb;
        float4 b1 = *(const float4*)(pb + 4);
        Bs[kc + 0][ar] = b0.x; Bs[kc + 1][ar] = b0.y;
        Bs[kc + 2][ar] = b0.z; Bs[kc + 3][ar] = b0.w;
        Bs[kc + 4][ar] = b1.x; Bs[kc + 5][ar] = b1.y;
        Bs[kc + 6][ar] = b1.z; Bs[kc + 7][ar] = b1.w;
        __syncthreads();
#pragma unroll
        for (int kk = 0; kk < 16; ++kk) {
            const float4* ap = (const float4*)&As[kk][ty * 8];
            const float4* bp = (const float4*)&Bs[kk][tx * 8];
            float4 av0 = ap[0], av1 = ap[1];
            float4 bv0 = bp[0], bv1 = bp[1];
            float a[8] = {av0.x, av0.y, av0.z, av0.w, av1.x, av1.y, av1.z, av1.w};
            float b[8] = {bv0.x, bv0.y, bv0.z, bv0.w, bv1.x, bv1.y, bv1.z, bv1.w};
#pragma unroll
            for (int i = 0; i < 8; ++i)
#pragma unroll
                for (int j = 0; j < 8; ++j) acc[i][j] += a[i] * b[j];
        }
        __syncthreads();
    }
#pragma unroll
    for (int i = 0; i < 8; ++i) {
        size_t row = (size_t)(bm + ty * 8 + i) * N + bn;
#pragma unroll
        for (int j = 0; j < 8; ++j) {
            int n = tx * 8 + j;
            C[row + n] = acc[i][j] + bias1[bn + n] + bias2[bn + n];
        }
    }
}

// ---------------------------------------------------------------- LSTM recurrence
// 64 WGs x 256 threads: wg 0..31 forward, 32..63 backward; WG owns 16 units.
// Publish: per step each WG stores 4x16B coherent chunks (4 h values each,
// mantissa-LSB forced to 1 as the "written" flag — ws poison 0xAA has LSB=0,
// comm addresses are write-once per launch). Consumers: 128 threads poll one
// 16B chunk each until all 4 LSBs are set. No tags, no fences, no atomics.
__global__ __launch_bounds__(256) void lstm_recur(
    const float* __restrict__ Zf, const float* __restrict__ Zb,
    const float* __restrict__ Whf, const float* __restrict__ Whb,
    float* commF, float* commB, float* __restrict__ hseq) {
    const int wg = blockIdx.x;
    const int dir = wg >> 5;
    const int g = wg & 31;
    const float* Z = dir ? Zb : Zf;
    const float* Wh = dir ? Whb : Whf;
    float* comm = dir ? commB : commF;

    const int tid = threadIdx.x;
    const int q = tid & 3;             // quarter of the 512-wide row
    const int r = tid >> 2;            // local row, r = 4*u + gate
    const int gate = r & 3;
    const int u = r >> 2;
    const int R = gate * HH + g * 16 + u;

    float w[128];
    {
        const float* wp = Wh + (size_t)R * HH + q * 128;
#pragma unroll
        for (int k = 0; k < 128; k += 4) {
            float4 v = *(const float4*)(wp + k);
            w[k] = v.x; w[k + 1] = v.y; w[k + 2] = v.z; w[k + 3] = v.w;
        }
    }

    // 4 q-sections of 136 floats: 16B-aligned sections, banks 0/8/16/24
    __shared__ float h_sh[2][544];

    const bool act = ((tid & 15) == 0);
    const int unit = g * 16 + (tid >> 4);          // unit for act lanes
    const int upad = unit + ((unit >> 7) << 3);    // padded LDS index
    const bool pollme = (tid < 128) && ((tid >> 2) != g);
    const int lidx = 4 * tid + ((tid >> 5) << 3);  // consumer LDS index (tid<128)

    float c = 0.f;

    for (int s = 0; s < TT; ++s) {
        const int t = dir ? (TT - 1 - s) : s;
        const int buf = s & 1;
        float zv = Z[(size_t)t * 2048 + R];        // h-independent: overlaps poll

        if (s == 0) {
            if (tid < 128) {
                v4f z4 = {0.f, 0.f, 0.f, 0.f};
                *(v4f*)&h_sh[0][lidx] = z4;
            }
        } else if (pollme) {
            const float* p = comm + (size_t)(s - 1) * HH + tid * 4;
            v4f v;
            int spins = 0;
            for (;;) {
                v = load_coherent16(p);
                unsigned m = __float_as_uint(v.x) & __float_as_uint(v.y) &
                             __float_as_uint(v.z) & __float_as_uint(v.w);
                if (m & 1u) break;
                if (++spins > 2) __builtin_amdgcn_s_sleep(1);
            }
            *(v4f*)&h_sh[buf][lidx] = v;
        }
        __syncthreads();

        float acc = 0.f;
        const float* hp = &h_sh[buf][q * 136];
#pragma unroll
        for (int k = 0; k < 128; k += 4) {
            float4 hv = *(const float4*)(hp + k);
            acc += w[k] * hv.x + w[k + 1] * hv.y + w[k + 2] * hv.z + w[k + 3] * hv.w;
        }
        acc += __shfl_xor(acc, 1);
        acc += __shfl_xor(acc, 2);
        float v = acc + zv;
        float gf_ = __shfl_down(v, 4);
        float gg_ = __shfl_down(v, 8);
        float go_ = __shfl_down(v, 12);

        // compute on ALL lanes (garbage on non-act lanes, unused)
        float si = 1.f / (1.f + __expf(-v));
        float sf = 1.f / (1.f + __expf(-gf_));
        float so = 1.f / (1.f + __expf(-go_));
        c = sf * c + si * tanhf(gg_);
        float h = so * tanhf(c);

        // gather this wave's 4 unit-h values into lane 0 of the wave
        v4f pub;
        pub.x = __shfl(h, 0);
        pub.y = __shfl(h, 16);
        pub.z = __shfl(h, 32);
        pub.w = __shfl(h, 48);
        if ((tid & 63) == 0) {
            pub.x = __uint_as_float(__float_as_uint(pub.x) | 1u);
            pub.y = __uint_as_float(__float_as_uint(pub.y) | 1u);
            pub.z = __uint_as_float(__float_as_uint(pub.z) | 1u);
            pub.w = __uint_as_float(__float_as_uint(pub.w) | 1u);
            store_coherent16(comm + (size_t)s * HH + g * 16 + ((tid >> 6) << 2), pub);
        }
        if (act) {
            hseq[(size_t)t * 1024 + dir * HH + unit] = h;
            h_sh[buf ^ 1][upad] = h;               // own unit, next step's buffer
        }
    }
}

// ---------------------------------------------------------------- final linear
__global__ void feats_kernel(const float* __restrict__ h1,
                             const float* __restrict__ lw,
                             const float* __restrict__ lb,
                             float* __restrict__ feats) {
    int t = blockIdx.x;
    int j = threadIdx.x;
    if (j < KK) {
        const float* a = h1 + (size_t)t * 1024;
        const float* b = lw + (size_t)j * 1024;
        float acc = 0.f;
        for (int k = 0; k < 1024; k += 4) {
            float4 av = *(const float4*)(a + k);
            float4 bv = *(const float4*)(b + k);
            acc += av.x * bv.x + av.y * bv.y + av.z * bv.z + av.w * bv.w;
        }
        feats[(size_t)t * KK + j] = acc + lb[j];
    }
}

// ---------------------------------------------------------------- CRF
__global__ __launch_bounds__(64) void crf_kernel(
    const float* __restrict__ feats, const float* __restrict__ trans,
    const int* __restrict__ tags, const int* __restrict__ seq_len,
    float* __restrict__ out) {
    __shared__ float alpha[KK];
    __shared__ float red[64];
    __shared__ float logz_sh;
    const int j = threadIdx.x;

    float Trow[KK];
    if (j < KK) {
#pragma unroll
        for (int i = 0; i < KK; ++i) Trow[i] = trans[(size_t)j * KK + i];
        alpha[j] = (j == START_TAG) ? 0.f : NEGV;
    }
    __syncthreads();

    for (int t = 0; t < TT; ++t) {
        float na = 0.f;
        if (j < KK) {
            float fj = feats[(size_t)t * KK + j];
            float m = -3.0e38f;
#pragma unroll
            for (int i = 0; i < KK; ++i) m = fmaxf(m, alpha[i] + Trow[i]);
            float ssum = 0.f;
#pragma unroll
            for (int i = 0; i < KK; ++i) ssum += __expf(alpha[i] + Trow[i] - m);
            na = fj + m + __logf(ssum);
        }
        __syncthreads();
        if (j < KK) alpha[j] = na;
        __syncthreads();
    }

    if (j == 0) {
        float m = -3.0e38f;
        for (int i = 0; i < KK; ++i) m = fmaxf(m, alpha[i] + trans[END_TAG * KK + i]);
        float ssum = 0.f;
        for (int i = 0; i < KK; ++i) ssum += __expf(alpha[i] + trans[END_TAG * KK + i] - m);
        logz_sh = m + __logf(ssum);
    }

    float sc = 0.f;
    for (int t = j; t < TT; t += 64) {
        int cur = tags[t];
        int prev = (t == 0) ? START_TAG : tags[t - 1];
        sc += trans[(size_t)cur * KK + prev] + feats[(size_t)t * KK + cur];
    }
    red[j] = sc;
    __syncthreads();
    if (j == 0) {
        float score = 0.f;
        for (int i = 0; i < 64; ++i) score += red[i];
        score += trans[END_TAG * KK + tags[TT - 1]];
        out[0] = (logz_sh - score) / (float)seq_len[0];
    }
}

// ---------------------------------------------------------------- launch
extern "C" void kernel_launch(void* const* d_in, const int* in_sizes, int n_in,
                              void* d_out, int out_size, void* d_ws, size_t ws_size,
                              hipStream_t stream) {
    const int* tokens = (const int*)d_in[0];
    const int* tags = (const int*)d_in[1];
    const int* seq_len = (const int*)d_in[2];
    const float* embed = (const float*)d_in[3];
    const float* w_ih_l0_f = (const float*)d_in[4];
    const float* w_hh_l0_f = (const float*)d_in[5];
    const float* b_ih_l0_f = (const float*)d_in[6];
    const float* b_hh_l0_f = (const float*)d_in[7];
    const float* w_ih_l0_b = (const float*)d_in[8];
    const float* w_hh_l0_b = (const float*)d_in[9];
    const float* b_ih_l0_b = (const float*)d_in[10];
    const float* b_hh_l0_b = (const float*)d_in[11];
    const float* w_ih_l1_f = (const float*)d_in[12];
    const float* w_hh_l1_f = (const float*)d_in[13];
    const float* b_ih_l1_f = (const float*)d_in[14];
    const float* b_hh_l1_f = (const float*)d_in[15];
    const float* w_ih_l1_b = (const float*)d_in[16];
    const float* w_hh_l1_b = (const float*)d_in[17];
    const float* b_ih_l1_b = (const float*)d_in[18];
    const float* b_hh_l1_b = (const float*)d_in[19];
    const float* lin_w = (const float*)d_in[20];
    const float* lin_b = (const float*)d_in[21];
    const float* transition = (const float*)d_in[22];
    float* out = (float*)d_out;

    char* ws = (char*)d_ws;
    float* x = (float*)ws;                                        //  2 MB
    float* Zf = (float*)(ws + (size_t)(2) * (1 << 20));           // 16 MB
    float* Zb = (float*)(ws + (size_t)(18) * (1 << 20));          // 16 MB
    float* h0 = (float*)(ws + (size_t)(34) * (1 << 20));          //  8 MB
    float* h1 = (float*)(ws + (size_t)(42) * (1 << 20));          //  8 MB
    float* feats = (float*)(ws + (size_t)(50) * (1 << 20));       // .4 MB
    float* commL0F = (float*)(ws + (size_t)(51) * (1 << 20));     //  4 MB each
    float* commL0B = (float*)(ws + (size_t)(55) * (1 << 20));
    float* commL1F = (float*)(ws + (size_t)(59) * (1 << 20));
    float* commL1B = (float*)(ws + (size_t)(63) * (1 << 20));

    gather_kernel<<<TT, EE, 0, stream>>>(tokens, embed, x);

    dim3 g16(16, 16);
    gemm_bt128<<<g16, 256, 0, stream>>>(x, w_ih_l0_f, Zf, TT, 2048, EE, b_ih_l0_f, b_hh_l0_f);
    gemm_bt128<<<g16, 256, 0, stream>>>(x, w_ih_l0_b, Zb, TT, 2048, EE, b_ih_l0_b, b_hh_l0_b);

    lstm_recur<<<64, 256, 0, stream>>>(Zf, Zb, w_hh_l0_f, w_hh_l0_b, commL0F, commL0B, h0);

    gemm_bt128<<<g16, 256, 0, stream>>>(h0, w_ih_l1_f, Zf, TT, 2048, 1024, b_ih_l1_f, b_hh_l1_f);
    gemm_bt128<<<g16, 256, 0, stream>>>(h0, w_ih_l1_b, Zb, TT, 2048, 1024, b_ih_l1_b, b_hh_l1_b);

    lstm_recur<<<64, 256, 0, stream>>>(Zf, Zb, w_hh_l1_f, w_hh_l1_b, commL1F, commL1B, h1);

    feats_kernel<<<TT, 64, 0, stream>>>(h1, lin_w, lin_b, feats);
    crf_kernel<<<1, 64, 0, stream>>>(feats, transition, tags, seq_len, out);
}